// Round 3
// baseline (375.322 us; speedup 1.0000x reference)
//
#include <hip/hip_runtime.h>

typedef float fx4 __attribute__((ext_vector_type(4)));
typedef short s16x8 __attribute__((ext_vector_type(8)));
typedef short s16x4 __attribute__((ext_vector_type(4)));
typedef unsigned short ushort_t;

__device__ __forceinline__ short f2bf(float f) {
  union { float f; unsigned u; } v; v.f = f;
  unsigned r = v.u + 0x7FFFu + ((v.u >> 16) & 1u);   // RNE to bf16
  return (short)(r >> 16);
}

__device__ __forceinline__ unsigned cvt_pk_bf16(float a, float b) {
  unsigned r;
  asm("v_cvt_pk_bf16_f32 %0, %1, %2" : "=v"(r) : "v"(a), "v"(b));
  return r;
}

// ---------------------------------------------------------------------------
// prep: all 5 weight transposes W[K][N] fp32 -> Wt[N][K] bf16 in one kernel.
// block segments: W1 256 | in_w 768 | out_w 256 | ff1 512 | ff2 512 = 2304
// ---------------------------------------------------------------------------
__global__ __launch_bounds__(256) void prep_kernel(
    const float* __restrict__ W1, const float* __restrict__ in_w,
    const float* __restrict__ out_w, const float* __restrict__ ff1_w,
    const float* __restrict__ ff2_w,
    ushort_t* __restrict__ W1t, ushort_t* __restrict__ in_wT,
    ushort_t* __restrict__ out_wT, ushort_t* __restrict__ ff1t,
    ushort_t* __restrict__ ff2t) {
  const int bid = blockIdx.x, t = threadIdx.x;
  const float* W; ushort_t* Wt; int K, N, base;
  if (bid < 256)       { W = W1;    Wt = W1t;    K = 256; N = 256; base = 0; }
  else if (bid < 1024) { W = in_w;  Wt = in_wT;  K = 256; N = 768; base = 256; }
  else if (bid < 1280) { W = out_w; Wt = out_wT; K = 256; N = 256; base = 1024; }
  else if (bid < 1792) { W = ff1_w; Wt = ff1t;   K = 256; N = 512; base = 1280; }
  else                 { W = ff2_w; Wt = ff2t;   K = 512; N = 256; base = 1792; }
  const int idx = (bid - base) * 256 + t;
  const int k = idx / N, n = idx - k * N;
  Wt[(size_t)n * K + k] = (ushort_t)f2bf(W[idx]);
}

// ---------------------------------------------------------------------------
// MFMA GEMM, BM=32, BN=256, BK=64, 256 thr (4 waves, wave w owns cols w*64..).
// 1-ahead register prefetch (2-phase). A bf16 [M,K] (or fp32 if AF32), Bt bf16
// [N,K]. Epilogue variants: TRANSOUT (bf16 C^T), LN (fused LayerNorm, needs
// N==256 and gridDim.x==1), else plain fp32/bf16 stores.
// ---------------------------------------------------------------------------
template<bool AF32, bool RELU, bool RES, bool F32OUT, bool BF16OUT,
         bool TRANSOUT, bool LN>
__global__ __launch_bounds__(256) void mgemm(
    const void* __restrict__ Av, const ushort_t* __restrict__ Bt,
    const float* __restrict__ bias, const float* __restrict__ res,
    const float* __restrict__ lns, const float* __restrict__ lnb,
    float* __restrict__ Cf, ushort_t* __restrict__ Cb, int M, int N, int K) {
  __shared__ __align__(16) ushort_t Asm[32 * 72];
  __shared__ __align__(16) ushort_t Bsm[256 * 72];
  __shared__ float red_s[32][4];
  __shared__ float red_q[32][4];
  const int t = threadIdx.x, lane = t & 63, wave = t >> 6;
  const int bm = blockIdx.y * 32, bn = blockIdx.x * 256;
  const int wn = wave * 64, fr = lane & 15, fq = lane >> 4;
  const int ar = t >> 3, aq = (t & 7) * 8;
  fx4 acc[2][4] = {};
  const float*    Agf = (const float*)Av    + (size_t)(bm + ar) * K + aq;
  const ushort_t* Agh = (const ushort_t*)Av + (size_t)(bm + ar) * K + aq;
  const ushort_t* Bg  = Bt + (size_t)(bn + t) * K;
  fx4 af0, af1; s16x8 a_r; s16x8 b_r[8];
  if constexpr (AF32) { af0 = *(const fx4*)Agf; af1 = *(const fx4*)(Agf + 4); }
  else a_r = *(const s16x8*)Agh;
  #pragma unroll
  for (int c = 0; c < 8; ++c) b_r[c] = *(const s16x8*)(Bg + c * 8);
  for (int k0 = 0; k0 < K; k0 += 64) {
    s16x8 aw;
    if constexpr (AF32) {
      union { s16x8 s; unsigned u[4]; } w;
      w.u[0] = cvt_pk_bf16(af0[0], af0[1]);
      w.u[1] = cvt_pk_bf16(af0[2], af0[3]);
      w.u[2] = cvt_pk_bf16(af1[0], af1[1]);
      w.u[3] = cvt_pk_bf16(af1[2], af1[3]);
      aw = w.s;
    } else aw = a_r;
    *(s16x8*)&Asm[ar * 72 + aq] = aw;
    #pragma unroll
    for (int c = 0; c < 8; ++c) *(s16x8*)&Bsm[t * 72 + c * 8] = b_r[c];
    __syncthreads();
    if (k0 + 64 < K) {                       // prefetch next tile into regs
      if constexpr (AF32) {
        af0 = *(const fx4*)(Agf + k0 + 64);
        af1 = *(const fx4*)(Agf + k0 + 68);
      } else a_r = *(const s16x8*)(Agh + k0 + 64);
      #pragma unroll
      for (int c = 0; c < 8; ++c)
        b_r[c] = *(const s16x8*)(Bg + k0 + 64 + c * 8);
    }
    #pragma unroll
    for (int kk = 0; kk < 2; ++kk) {
      s16x8 afr[2], bfr[4];
      #pragma unroll
      for (int mf = 0; mf < 2; ++mf)
        afr[mf] = *(const s16x8*)&Asm[(mf * 16 + fr) * 72 + kk * 32 + fq * 8];
      #pragma unroll
      for (int nf = 0; nf < 4; ++nf)
        bfr[nf] = *(const s16x8*)&Bsm[(wn + nf * 16 + fr) * 72 + kk * 32 + fq * 8];
      #pragma unroll
      for (int mf = 0; mf < 2; ++mf)
        #pragma unroll
        for (int nf = 0; nf < 4; ++nf)
          acc[mf][nf] = __builtin_amdgcn_mfma_f32_16x16x32_bf16(
              afr[mf], bfr[nf], acc[mf][nf], 0, 0, 0);
    }
    __syncthreads();
  }
  if constexpr (TRANSOUT) {
    #pragma unroll
    for (int mf = 0; mf < 2; ++mf)
      #pragma unroll
      for (int nf = 0; nf < 4; ++nf) {
        const int col = bn + wn + nf * 16 + fr;
        const float bb = bias[col];
        s16x4 w;
        #pragma unroll
        for (int r = 0; r < 4; ++r) w[r] = f2bf(acc[mf][nf][r] + bb);
        *(s16x4*)&Cb[(size_t)col * M + bm + mf * 16 + fq * 4] = w;
      }
  } else if constexpr (LN) {
    float v[2][4][4];
    #pragma unroll
    for (int mf = 0; mf < 2; ++mf)
      #pragma unroll
      for (int nf = 0; nf < 4; ++nf) {
        const int col = wn + nf * 16 + fr;
        #pragma unroll
        for (int r = 0; r < 4; ++r) {
          const int row = bm + mf * 16 + fq * 4 + r;
          float x = acc[mf][nf][r] + bias[col];
          if constexpr (RES) x += res[(size_t)row * 256 + col];
          v[mf][nf][r] = x;
        }
      }
    #pragma unroll
    for (int mf = 0; mf < 2; ++mf)
      #pragma unroll
      for (int r = 0; r < 4; ++r) {
        float s = v[mf][0][r] + v[mf][1][r] + v[mf][2][r] + v[mf][3][r];
        float q = v[mf][0][r] * v[mf][0][r] + v[mf][1][r] * v[mf][1][r] +
                  v[mf][2][r] * v[mf][2][r] + v[mf][3][r] * v[mf][3][r];
        #pragma unroll
        for (int off = 1; off < 16; off <<= 1) {
          s += __shfl_xor(s, off, 64);
          q += __shfl_xor(q, off, 64);
        }
        if (fr == 0) {
          red_s[mf * 16 + fq * 4 + r][wave] = s;
          red_q[mf * 16 + fq * 4 + r][wave] = q;
        }
      }
    __syncthreads();
    #pragma unroll
    for (int mf = 0; mf < 2; ++mf)
      #pragma unroll
      for (int r = 0; r < 4; ++r) {
        const int rl = mf * 16 + fq * 4 + r;
        const float st = red_s[rl][0] + red_s[rl][1] + red_s[rl][2] + red_s[rl][3];
        const float qt = red_q[rl][0] + red_q[rl][1] + red_q[rl][2] + red_q[rl][3];
        const float mu = st * (1.f / 256.f);
        const float var = qt * (1.f / 256.f) - mu * mu;
        const float rr = rsqrtf(var + 1e-5f);
        const int row = bm + rl;
        #pragma unroll
        for (int nf = 0; nf < 4; ++nf) {
          const int col = wn + nf * 16 + fr;
          const float o = (v[mf][nf][r] - mu) * rr * lns[col] + lnb[col];
          if constexpr (F32OUT) Cf[(size_t)row * 256 + col] = o;
          if constexpr (BF16OUT) Cb[(size_t)row * 256 + col] = (ushort_t)f2bf(o);
        }
      }
  } else {
    #pragma unroll
    for (int mf = 0; mf < 2; ++mf)
      #pragma unroll
      for (int nf = 0; nf < 4; ++nf) {
        const int col = bn + wn + nf * 16 + fr;
        const float bb = bias[col];
        #pragma unroll
        for (int r = 0; r < 4; ++r) {
          const int row = bm + mf * 16 + fq * 4 + r;
          float x = acc[mf][nf][r] + bb;
          if constexpr (RES) x += res[(size_t)row * N + col];
          if constexpr (RELU) x = fmaxf(x, 0.f);
          if constexpr (F32OUT) Cf[(size_t)row * N + col] = x;
          if constexpr (BF16OUT) Cb[(size_t)row * N + col] = (ushort_t)f2bf(x);
        }
      }
  }
}

// ---------------------------------------------------------------------------
// p = relu(adj @ x): full-K (8192), BM=32, grid 256, fused relu epilogue,
// 1-ahead prefetch, cvt_pk fp32->bf16 staging. B = xT bf16 [256][8192].
// ---------------------------------------------------------------------------
__global__ __launch_bounds__(256) void adjmm_kernel(
    const float* __restrict__ adj, const ushort_t* __restrict__ xT,
    float* __restrict__ p, ushort_t* __restrict__ p_bf) {
  __shared__ __align__(16) ushort_t Asm[32 * 72];
  __shared__ __align__(16) ushort_t Bsm[256 * 72];
  const int t = threadIdx.x, lane = t & 63, wave = t >> 6;
  const int bm = blockIdx.x * 32;
  const int wn = wave * 64, fr = lane & 15, fq = lane >> 4;
  const int ar = t >> 3, aq = (t & 7) * 8;
  fx4 acc[2][4] = {};
  const float*    Ag = adj + (size_t)(bm + ar) * 8192 + aq;
  const ushort_t* Bg = xT + (size_t)t * 8192;
  fx4 af0 = *(const fx4*)Ag;
  fx4 af1 = *(const fx4*)(Ag + 4);
  s16x8 b_r[8];
  #pragma unroll
  for (int c = 0; c < 8; ++c) b_r[c] = *(const s16x8*)(Bg + c * 8);
  for (int kt = 0; kt < 128; ++kt) {
    union { s16x8 s; unsigned u[4]; } w;
    w.u[0] = cvt_pk_bf16(af0[0], af0[1]);
    w.u[1] = cvt_pk_bf16(af0[2], af0[3]);
    w.u[2] = cvt_pk_bf16(af1[0], af1[1]);
    w.u[3] = cvt_pk_bf16(af1[2], af1[3]);
    *(s16x8*)&Asm[ar * 72 + aq] = w.s;
    #pragma unroll
    for (int c = 0; c < 8; ++c) *(s16x8*)&Bsm[t * 72 + c * 8] = b_r[c];
    __syncthreads();
    if (kt < 127) {
      const int k0 = (kt + 1) * 64;
      af0 = *(const fx4*)(Ag + k0);
      af1 = *(const fx4*)(Ag + k0 + 4);
      #pragma unroll
      for (int c = 0; c < 8; ++c) b_r[c] = *(const s16x8*)(Bg + k0 + c * 8);
    }
    #pragma unroll
    for (int kk = 0; kk < 2; ++kk) {
      s16x8 afr[2], bfr[4];
      #pragma unroll
      for (int mf = 0; mf < 2; ++mf)
        afr[mf] = *(const s16x8*)&Asm[(mf * 16 + fr) * 72 + kk * 32 + fq * 8];
      #pragma unroll
      for (int nf = 0; nf < 4; ++nf)
        bfr[nf] = *(const s16x8*)&Bsm[(wn + nf * 16 + fr) * 72 + kk * 32 + fq * 8];
      #pragma unroll
      for (int mf = 0; mf < 2; ++mf)
        #pragma unroll
        for (int nf = 0; nf < 4; ++nf)
          acc[mf][nf] = __builtin_amdgcn_mfma_f32_16x16x32_bf16(
              afr[mf], bfr[nf], acc[mf][nf], 0, 0, 0);
    }
    __syncthreads();
  }
  #pragma unroll
  for (int mf = 0; mf < 2; ++mf)
    #pragma unroll
    for (int nf = 0; nf < 4; ++nf) {
      const int col = wn + nf * 16 + fr;
      #pragma unroll
      for (int r = 0; r < 4; ++r) {
        const int row = bm + mf * 16 + fq * 4 + r;
        const float v = fmaxf(acc[mf][nf][r], 0.f);
        p[(size_t)row * 256 + col] = v;
        p_bf[(size_t)row * 256 + col] = (ushort_t)f2bf(v);
      }
    }
}

// ---------------------------------------------------------------------------
// Fused attention: one block per (graph, head). K,V,S all in LDS (~135 KB).
// Phase1: scores (k-range split across thread halves) + softmax in LDS.
// Phase2: PV with d-range split (as round-2 attB). Emits bf16 attout.
// ---------------------------------------------------------------------------
__global__ __launch_bounds__(256) void att_fused(
    const float* __restrict__ qkv, ushort_t* __restrict__ attout) {
  __shared__ float k_s[128][68];
  __shared__ float v_s[128][68];
  __shared__ float s_s[128][129];
  __shared__ float pm[2][128];
  __shared__ float ps[2][128];
  const int bh = blockIdx.x, b = bh >> 2, h = bh & 3;
  const int t = threadIdx.x;
  const float* base = qkv + (size_t)b * 128 * 768 + h * 64;
  for (int e = t; e < 128 * 64; e += 256) {
    const int n = e >> 6, d = e & 63;
    k_s[n][d] = base[(size_t)n * 768 + 256 + d];
    v_s[n][d] = base[(size_t)n * 768 + 512 + d];
  }
  const int row = t & 127, kh = t >> 7;
  fx4 qr[16];
  const fx4* qrow = (const fx4*)(base + (size_t)row * 768);
  #pragma unroll
  for (int c = 0; c < 16; ++c) qr[c] = qrow[c];
  __syncthreads();
  float m = -1e30f;
  for (int j = 0; j < 64; ++j) {
    const int jj = kh * 64 + j;
    const fx4* kr = (const fx4*)&k_s[jj][0];
    float s0 = 0.f, s1 = 0.f, s2 = 0.f, s3 = 0.f;
    #pragma unroll
    for (int c = 0; c < 16; c += 4) {
      fx4 k0 = kr[c], k1 = kr[c + 1], k2 = kr[c + 2], k3 = kr[c + 3];
      s0 += qr[c][0]*k0[0] + qr[c][1]*k0[1] + qr[c][2]*k0[2] + qr[c][3]*k0[3];
      s1 += qr[c+1][0]*k1[0] + qr[c+1][1]*k1[1] + qr[c+1][2]*k1[2] + qr[c+1][3]*k1[3];
      s2 += qr[c+2][0]*k2[0] + qr[c+2][1]*k2[1] + qr[c+2][2]*k2[2] + qr[c+2][3]*k2[3];
      s3 += qr[c+3][0]*k3[0] + qr[c+3][1]*k3[1] + qr[c+3][2]*k3[2] + qr[c+3][3]*k3[3];
    }
    const float s = (s0 + s1 + s2 + s3) * 0.125f;
    s_s[row][jj] = s;
    m = fmaxf(m, s);
  }
  pm[kh][row] = m;
  __syncthreads();
  const float m2 = fmaxf(pm[0][row], pm[1][row]);
  float sum = 0.f;
  for (int j = 0; j < 64; ++j) {
    const int jj = kh * 64 + j;
    const float e = __expf(s_s[row][jj] - m2);
    s_s[row][jj] = e;
    sum += e;
  }
  ps[kh][row] = sum;
  __syncthreads();
  const int row2 = t >> 1, dh = (t & 1) * 32;
  const float inv = 1.f / (ps[0][row2] + ps[1][row2]);
  fx4 acc4[8] = {};
  for (int k = 0; k < 128; ++k) {
    const float e = s_s[row2][k];
    const fx4* vr = (const fx4*)&v_s[k][dh];
    #pragma unroll
    for (int c = 0; c < 8; ++c) acc4[c] += e * vr[c];
  }
  ushort_t* orow = attout + (size_t)(b * 128 + row2) * 256 + h * 64 + dh;
  #pragma unroll
  for (int c = 0; c < 8; ++c) {
    const fx4 v = acc4[c] * inv;
    s16x4 w;
    #pragma unroll
    for (int j = 0; j < 4; ++j) w[j] = f2bf(v[j]);
    *(s16x4*)(orow + c * 4) = w;
  }
}

// ---------------------------------------------------------------------------
// Pool: 4 blocks per graph, each sums 32 rows.
// ---------------------------------------------------------------------------
__global__ __launch_bounds__(256) void pool_kernel(
    const float* __restrict__ y2, float* __restrict__ pooled4) {
  const int bq = blockIdx.x;
  const int b = bq >> 2, q = bq & 3, h = threadIdx.x;
  const float* pb = y2 + ((size_t)b * 128 + q * 32) * 256 + h;
  float s = 0.f;
  for (int n = 0; n < 32; ++n) s += pb[(size_t)n * 256];
  pooled4[(size_t)bq * 256 + h] = s;
}

__global__ __launch_bounds__(256) void head_kernel(
    const float* __restrict__ pooled4, const float* __restrict__ W3,
    const float* __restrict__ b3, const float* __restrict__ W4,
    const float* __restrict__ b4, float* __restrict__ out) {
  __shared__ float sp[256];
  __shared__ float t1[256];
  __shared__ float logits[16];
  const int b = blockIdx.x, h = threadIdx.x;
  sp[h] = pooled4[(size_t)(b * 4 + 0) * 256 + h] +
          pooled4[(size_t)(b * 4 + 1) * 256 + h] +
          pooled4[(size_t)(b * 4 + 2) * 256 + h] +
          pooled4[(size_t)(b * 4 + 3) * 256 + h];
  __syncthreads();
  float a = b3[h];
  for (int k = 0; k < 256; ++k) a += sp[k] * W3[k * 256 + h];
  t1[h] = fmaxf(a, 0.f);
  __syncthreads();
  if (h < 16) {
    float o = b4[h];
    for (int j = 0; j < 256; ++j) o += t1[j] * W4[j * 16 + h];
    logits[h] = o;
  }
  __syncthreads();
  if (h < 16) {
    float mm = -1e30f;
    #pragma unroll
    for (int c = 0; c < 16; ++c) mm = fmaxf(mm, logits[c]);
    float se = 0.f;
    #pragma unroll
    for (int c = 0; c < 16; ++c) se += __expf(logits[c] - mm);
    out[b * 16 + h] = logits[h] - mm - logf(se);
  }
}

// ---------------------------------------------------------------------------
extern "C" void kernel_launch(void* const* d_in, const int* in_sizes, int n_in,
                              void* d_out, int out_size, void* d_ws, size_t ws_size,
                              hipStream_t stream) {
  const float* x_in  = (const float*)d_in[0];
  const float* adj   = (const float*)d_in[1];
  const float* W1    = (const float*)d_in[4];
  const float* b1    = (const float*)d_in[5];
  const float* in_w  = (const float*)d_in[6];
  const float* in_b  = (const float*)d_in[7];
  const float* out_w = (const float*)d_in[8];
  const float* out_b = (const float*)d_in[9];
  const float* ln1_s = (const float*)d_in[10];
  const float* ln1_b = (const float*)d_in[11];
  const float* ff1_w = (const float*)d_in[12];
  const float* ff1_b = (const float*)d_in[13];
  const float* ff2_w = (const float*)d_in[14];
  const float* ff2_b = (const float*)d_in[15];
  const float* ln2_s = (const float*)d_in[16];
  const float* ln2_b = (const float*)d_in[17];
  const float* W3    = (const float*)d_in[18];
  const float* b3    = (const float*)d_in[19];
  const float* W4    = (const float*)d_in[20];
  const float* b4    = (const float*)d_in[21];
  char* ws = (char*)d_ws;
  const size_t MB = 1ull << 20;
  ushort_t* xT      = (ushort_t*)(ws);                 // 4 MB
  ushort_t* W1t     = (ushort_t*)(ws + 4 * MB);
  ushort_t* in_wT   = (ushort_t*)(ws + 4 * MB + 131072);
  ushort_t* out_wT  = (ushort_t*)(ws + 4 * MB + 524288);
  ushort_t* ff1t    = (ushort_t*)(ws + 4 * MB + 655360);
  ushort_t* ff2t    = (ushort_t*)(ws + 4 * MB + 917504);
  float*    p       = (float*)(ws + 8 * MB);           // 8 MB
  ushort_t* p_bf    = (ushort_t*)(ws + 16 * MB);       // 4 MB
  float*    qkvb    = (float*)(ws + 20 * MB);          // 24 MB
  ushort_t* attout  = (ushort_t*)(ws + 44 * MB);       // 4 MB
  float*    y       = (float*)(ws + 48 * MB);          // 8 MB
  ushort_t* y_bf    = (ushort_t*)(ws + 56 * MB);       // 4 MB
  ushort_t* f1_bf   = (ushort_t*)(ws + 60 * MB);       // 8 MB
  float*    y2      = (float*)(ws + 68 * MB);          // 8 MB
  float*    pooled4 = (float*)(ws + 76 * MB);          // 256 KB
  float*    outp    = (float*)d_out;
  (void)in_sizes; (void)n_in; (void)out_size; (void)ws_size;

  prep_kernel<<<2304, 256, 0, stream>>>(W1, in_w, out_w, ff1_w, ff2_w,
                                        W1t, in_wT, out_wT, ff1t, ff2t);
  // fc1: xT = (x_in@W1+b1)^T bf16 (A staged fp32->bf16 in-kernel)
  mgemm<true, false, false, false, false, true, false>
      <<<dim3(1, 256), 256, 0, stream>>>(
      x_in, W1t, b1, nullptr, nullptr, nullptr, nullptr, xT, 8192, 256, 256);
  // p = relu(adj @ x), p_bf alongside
  adjmm_kernel<<<256, 256, 0, stream>>>(adj, xT, p, p_bf);
  // qkv (fp32 out for attention)
  mgemm<false, false, false, true, false, false, false>
      <<<dim3(3, 256), 256, 0, stream>>>(
      p_bf, in_wT, in_b, nullptr, nullptr, nullptr, qkvb, nullptr, 8192, 768, 256);
  // attention (fused)
  att_fused<<<256, 256, 0, stream>>>(qkvb, attout);
  // out projection + residual(p) + LN1 -> y (fp32) + y_bf (bf16)
  mgemm<false, false, true, true, true, false, true>
      <<<dim3(1, 256), 256, 0, stream>>>(
      attout, out_wT, out_b, p, ln1_s, ln1_b, y, y_bf, 8192, 256, 256);
  // ff1 (relu, bf16 out)
  mgemm<false, true, false, false, true, false, false>
      <<<dim3(2, 256), 256, 0, stream>>>(
      f1_bf == nullptr ? nullptr : y_bf, ff1t, ff1_b, nullptr, nullptr, nullptr,
      nullptr, f1_bf, 8192, 512, 256);
  // ff2 + residual(y) + LN2 -> y2
  mgemm<false, false, true, true, false, false, true>
      <<<dim3(1, 256), 256, 0, stream>>>(
      f1_bf, ff2t, ff2_b, y, ln2_s, ln2_b, y2, nullptr, 8192, 256, 512);
  // pooling + classifier head
  pool_kernel<<<256, 256, 0, stream>>>(y2, pooled4);
  head_kernel<<<64, 256, 0, stream>>>(pooled4, W3, b3, W4, b4, outp);
}

// Round 4
// 296.312 us; speedup vs baseline: 1.2666x; 1.2666x over previous
//
#include <hip/hip_runtime.h>

typedef float fx4 __attribute__((ext_vector_type(4)));
typedef short s16x8 __attribute__((ext_vector_type(8)));
typedef short s16x4 __attribute__((ext_vector_type(4)));
typedef unsigned short ushort_t;

__device__ __forceinline__ short f2bf(float f) {
  union { float f; unsigned u; } v; v.f = f;
  unsigned r = v.u + 0x7FFFu + ((v.u >> 16) & 1u);   // RNE to bf16
  return (short)(r >> 16);
}

__device__ __forceinline__ unsigned cvt_pk_bf16(float a, float b) {
  unsigned r;
  asm("v_cvt_pk_bf16_f32 %0, %1, %2" : "=v"(r) : "v"(a), "v"(b));
  return r;
}

__device__ __forceinline__ s16x8 cvt8(fx4 a, fx4 b) {
  union { s16x8 s; unsigned u[4]; } w;
  w.u[0] = cvt_pk_bf16(a[0], a[1]);
  w.u[1] = cvt_pk_bf16(a[2], a[3]);
  w.u[2] = cvt_pk_bf16(b[0], b[1]);
  w.u[3] = cvt_pk_bf16(b[2], b[3]);
  return w.s;
}

// ---------------------------------------------------------------------------
// prep: all 5 weight transposes W[K][N] fp32 -> Wt[N][K] bf16 in one kernel.
// ---------------------------------------------------------------------------
__global__ __launch_bounds__(256) void prep_kernel(
    const float* __restrict__ W1, const float* __restrict__ in_w,
    const float* __restrict__ out_w, const float* __restrict__ ff1_w,
    const float* __restrict__ ff2_w,
    ushort_t* __restrict__ W1t, ushort_t* __restrict__ in_wT,
    ushort_t* __restrict__ out_wT, ushort_t* __restrict__ ff1t,
    ushort_t* __restrict__ ff2t) {
  const int bid = blockIdx.x, t = threadIdx.x;
  const float* W; ushort_t* Wt; int K, N, base;
  if (bid < 256)       { W = W1;    Wt = W1t;    K = 256; N = 256; base = 0; }
  else if (bid < 1024) { W = in_w;  Wt = in_wT;  K = 256; N = 768; base = 256; }
  else if (bid < 1280) { W = out_w; Wt = out_wT; K = 256; N = 256; base = 1024; }
  else if (bid < 1792) { W = ff1_w; Wt = ff1t;   K = 256; N = 512; base = 1280; }
  else                 { W = ff2_w; Wt = ff2t;   K = 512; N = 256; base = 1792; }
  const int idx = (bid - base) * 256 + t;
  const int k = idx / N, n = idx - k * N;
  Wt[(size_t)n * K + k] = (ushort_t)f2bf(W[idx]);
}

// ---------------------------------------------------------------------------
// MFMA GEMM, BM=32, BN=256, BK=64, 256 thr (4 waves by n; wave w cols w*64..).
// A read DIRECTLY global->reg in fragment layout (no Asm LDS):
//   frag(mf,kk) lane l = A[bm+mf*16+(l&15)][k0+kk*32+(l>>4)*8 ..+7]
//   -> per frag 16 rows x 128B(bf16)/contiguous: coalesced; x4 wave redundancy
//      is L1-resident. AF32: fp32 A, cvt_pk in-reg.
// B staged in LDS coalesced (8 lanes x 16B = 128B/row), 1-ahead reg prefetch.
// Epilogues: TRANSOUT (bf16 C^T), LN (fused LayerNorm, gridDim.x==1), plain.
// ---------------------------------------------------------------------------
template<bool AF32, bool RELU, bool RES, bool F32OUT, bool BF16OUT,
         bool TRANSOUT, bool LN>
__global__ __launch_bounds__(256) void mgemm(
    const void* __restrict__ Av, const ushort_t* __restrict__ Bt,
    const float* __restrict__ bias, const float* __restrict__ res,
    const float* __restrict__ lns, const float* __restrict__ lnb,
    float* __restrict__ Cf, ushort_t* __restrict__ Cb, int M, int N, int K) {
  __shared__ __align__(16) ushort_t Bsm[256 * 72];
  __shared__ float red_s[32][4];
  __shared__ float red_q[32][4];
  const int t = threadIdx.x, lane = t & 63, wave = t >> 6;
  const int bm = blockIdx.y * 32, bn = blockIdx.x * 256;
  const int wn = wave * 64, fr = lane & 15, fq = lane >> 4;
  fx4 acc[2][4] = {};
  // B coalesced staging: pass p: row p*32+(t>>3), k-off (t&7)*8
  const int brow = t >> 3, bko = (t & 7) * 8;
  const ushort_t* Bg = Bt + (size_t)(bn + brow) * K + bko;
  const float*    Agf = (const float*)Av;
  const ushort_t* Agh = (const ushort_t*)Av;
  s16x8 b_r[8];
  #pragma unroll
  for (int p = 0; p < 8; ++p)
    b_r[p] = *(const s16x8*)(Bg + (size_t)p * 32 * K);
  for (int k0 = 0; k0 < K; k0 += 64) {
    #pragma unroll
    for (int p = 0; p < 8; ++p)
      *(s16x8*)&Bsm[(p * 32 + brow) * 72 + bko] = b_r[p];
    __syncthreads();
    if (k0 + 64 < K) {
      #pragma unroll
      for (int p = 0; p < 8; ++p)
        b_r[p] = *(const s16x8*)(Bg + (size_t)p * 32 * K + k0 + 64);
    }
    #pragma unroll
    for (int kk = 0; kk < 2; ++kk) {
      s16x8 afr[2], bfr[4];
      #pragma unroll
      for (int mf = 0; mf < 2; ++mf) {
        const size_t off = (size_t)(bm + mf * 16 + fr) * K + k0 + kk * 32 + fq * 8;
        if constexpr (AF32)
          afr[mf] = cvt8(*(const fx4*)(Agf + off), *(const fx4*)(Agf + off + 4));
        else
          afr[mf] = *(const s16x8*)(Agh + off);
      }
      #pragma unroll
      for (int nf = 0; nf < 4; ++nf)
        bfr[nf] = *(const s16x8*)&Bsm[(wn + nf * 16 + fr) * 72 + kk * 32 + fq * 8];
      #pragma unroll
      for (int mf = 0; mf < 2; ++mf)
        #pragma unroll
        for (int nf = 0; nf < 4; ++nf)
          acc[mf][nf] = __builtin_amdgcn_mfma_f32_16x16x32_bf16(
              afr[mf], bfr[nf], acc[mf][nf], 0, 0, 0);
    }
    __syncthreads();
  }
  if constexpr (TRANSOUT) {
    #pragma unroll
    for (int mf = 0; mf < 2; ++mf)
      #pragma unroll
      for (int nf = 0; nf < 4; ++nf) {
        const int col = bn + wn + nf * 16 + fr;
        const float bb = bias[col];
        s16x4 w;
        #pragma unroll
        for (int r = 0; r < 4; ++r) w[r] = f2bf(acc[mf][nf][r] + bb);
        *(s16x4*)&Cb[(size_t)col * M + bm + mf * 16 + fq * 4] = w;
      }
  } else if constexpr (LN) {
    float v[2][4][4];
    #pragma unroll
    for (int mf = 0; mf < 2; ++mf)
      #pragma unroll
      for (int nf = 0; nf < 4; ++nf) {
        const int col = wn + nf * 16 + fr;
        #pragma unroll
        for (int r = 0; r < 4; ++r) {
          const int row = bm + mf * 16 + fq * 4 + r;
          float x = acc[mf][nf][r] + bias[col];
          if constexpr (RES) x += res[(size_t)row * 256 + col];
          v[mf][nf][r] = x;
        }
      }
    #pragma unroll
    for (int mf = 0; mf < 2; ++mf)
      #pragma unroll
      for (int r = 0; r < 4; ++r) {
        float s = v[mf][0][r] + v[mf][1][r] + v[mf][2][r] + v[mf][3][r];
        float q = v[mf][0][r] * v[mf][0][r] + v[mf][1][r] * v[mf][1][r] +
                  v[mf][2][r] * v[mf][2][r] + v[mf][3][r] * v[mf][3][r];
        #pragma unroll
        for (int off = 1; off < 16; off <<= 1) {
          s += __shfl_xor(s, off, 64);
          q += __shfl_xor(q, off, 64);
        }
        if (fr == 0) {
          red_s[mf * 16 + fq * 4 + r][wave] = s;
          red_q[mf * 16 + fq * 4 + r][wave] = q;
        }
      }
    __syncthreads();
    #pragma unroll
    for (int mf = 0; mf < 2; ++mf)
      #pragma unroll
      for (int r = 0; r < 4; ++r) {
        const int rl = mf * 16 + fq * 4 + r;
        const float st = red_s[rl][0] + red_s[rl][1] + red_s[rl][2] + red_s[rl][3];
        const float qt = red_q[rl][0] + red_q[rl][1] + red_q[rl][2] + red_q[rl][3];
        const float mu = st * (1.f / 256.f);
        const float var = qt * (1.f / 256.f) - mu * mu;
        const float rr = rsqrtf(var + 1e-5f);
        const int row = bm + rl;
        #pragma unroll
        for (int nf = 0; nf < 4; ++nf) {
          const int col = wn + nf * 16 + fr;
          const float o = (v[mf][nf][r] - mu) * rr * lns[col] + lnb[col];
          if constexpr (F32OUT) Cf[(size_t)row * 256 + col] = o;
          if constexpr (BF16OUT) Cb[(size_t)row * 256 + col] = (ushort_t)f2bf(o);
        }
      }
  } else {
    #pragma unroll
    for (int mf = 0; mf < 2; ++mf)
      #pragma unroll
      for (int nf = 0; nf < 4; ++nf) {
        const int col = bn + wn + nf * 16 + fr;
        const float bb = bias[col];
        #pragma unroll
        for (int r = 0; r < 4; ++r) {
          const int row = bm + mf * 16 + fq * 4 + r;
          float x = acc[mf][nf][r] + bb;
          if constexpr (RES) x += res[(size_t)row * N + col];
          if constexpr (RELU) x = fmaxf(x, 0.f);
          if constexpr (F32OUT) Cf[(size_t)row * N + col] = x;
          if constexpr (BF16OUT) Cb[(size_t)row * N + col] = (ushort_t)f2bf(x);
        }
      }
  }
}

// ---------------------------------------------------------------------------
// adjmm: part[kh] = adj[:, kh*2048:+2048] @ x[kh-chunk].  BM=64, K-split 4,
// grid (4,128)=512 blocks (2/CU, 8 waves/CU). A (adj fp32) global->reg->cvt
// directly in fragment layout (16 rows x 128B coalesced, x4 wave redundancy
// L1-hit). B (xT bf16 [256][8192]) LDS-staged coalesced, 1-ahead prefetch.
// ---------------------------------------------------------------------------
__global__ __launch_bounds__(256, 2) void adjmm_kernel(
    const float* __restrict__ adj, const ushort_t* __restrict__ xT,
    float* __restrict__ part) {
  __shared__ __align__(16) ushort_t Bsm[256 * 72];
  const int t = threadIdx.x, lane = t & 63, wave = t >> 6;
  const int bm = blockIdx.y * 64, kh = blockIdx.x;
  const int wn = wave * 64, fr = lane & 15, fq = lane >> 4;
  fx4 acc[4][4] = {};
  const int brow = t >> 3, bko = (t & 7) * 8;
  const ushort_t* Bg = xT + (size_t)brow * 8192 + kh * 2048 + bko;
  // lane A base: row (bm+fr), k base kh*2048 + fq*8
  const float* Ag = adj + (size_t)(bm + fr) * 8192 + kh * 2048 + fq * 8;
  s16x8 b_r[8];
  fx4 a_r[4][2][2];                       // [mf][kk][half]
  #pragma unroll
  for (int p = 0; p < 8; ++p)
    b_r[p] = *(const s16x8*)(Bg + (size_t)p * 32 * 8192);
  #pragma unroll
  for (int mf = 0; mf < 4; ++mf)
    #pragma unroll
    for (int kk = 0; kk < 2; ++kk) {
      const float* ap = Ag + (size_t)mf * 16 * 8192 + kk * 32;
      a_r[mf][kk][0] = *(const fx4*)ap;
      a_r[mf][kk][1] = *(const fx4*)(ap + 4);
    }
  for (int kt = 0; kt < 32; ++kt) {
    #pragma unroll
    for (int p = 0; p < 8; ++p)
      *(s16x8*)&Bsm[(p * 32 + brow) * 72 + bko] = b_r[p];
    __syncthreads();
    // consume A regs into bf16 frags, then reissue loads for kt+1
    s16x8 af[4][2];
    #pragma unroll
    for (int mf = 0; mf < 4; ++mf)
      #pragma unroll
      for (int kk = 0; kk < 2; ++kk)
        af[mf][kk] = cvt8(a_r[mf][kk][0], a_r[mf][kk][1]);
    if (kt < 31) {
      const int knx = (kt + 1) * 64;
      #pragma unroll
      for (int p = 0; p < 8; ++p)
        b_r[p] = *(const s16x8*)(Bg + (size_t)p * 32 * 8192 + knx);
      #pragma unroll
      for (int mf = 0; mf < 4; ++mf)
        #pragma unroll
        for (int kk = 0; kk < 2; ++kk) {
          const float* ap = Ag + (size_t)mf * 16 * 8192 + knx + kk * 32;
          a_r[mf][kk][0] = *(const fx4*)ap;
          a_r[mf][kk][1] = *(const fx4*)(ap + 4);
        }
    }
    #pragma unroll
    for (int kk = 0; kk < 2; ++kk) {
      s16x8 bfr[4];
      #pragma unroll
      for (int nf = 0; nf < 4; ++nf)
        bfr[nf] = *(const s16x8*)&Bsm[(wn + nf * 16 + fr) * 72 + kk * 32 + fq * 8];
      #pragma unroll
      for (int mf = 0; mf < 4; ++mf)
        #pragma unroll
        for (int nf = 0; nf < 4; ++nf)
          acc[mf][nf] = __builtin_amdgcn_mfma_f32_16x16x32_bf16(
              af[mf][kk], bfr[nf], acc[mf][nf], 0, 0, 0);
    }
    __syncthreads();
  }
  float* po = part + (size_t)kh * (8192ull * 256ull);
  #pragma unroll
  for (int mf = 0; mf < 4; ++mf)
    #pragma unroll
    for (int nf = 0; nf < 4; ++nf)
      #pragma unroll
      for (int r = 0; r < 4; ++r)
        po[(size_t)(bm + mf * 16 + fq * 4 + r) * 256 + wn + nf * 16 + fr] =
            acc[mf][nf][r];
}

__global__ __launch_bounds__(256) void relu_reduce4(
    const float* __restrict__ part, float* __restrict__ p,
    ushort_t* __restrict__ pb) {
  const size_t i = ((size_t)blockIdx.x * 256 + threadIdx.x) * 4;
  const size_t S = 8192ull * 256ull;
  fx4 v = *(const fx4*)(part + i);
  v += *(const fx4*)(part + S + i);
  v += *(const fx4*)(part + 2 * S + i);
  v += *(const fx4*)(part + 3 * S + i);
  #pragma unroll
  for (int c = 0; c < 4; ++c) v[c] = fmaxf(v[c], 0.f);
  *(fx4*)(p + i) = v;
  s16x4 w;
  #pragma unroll
  for (int c = 0; c < 4; ++c) w[c] = f2bf(v[c]);
  *(s16x4*)(pb + i) = w;
}

// ---------------------------------------------------------------------------
// Fused attention: one block per (graph, head). K,V,S all in LDS.
// ---------------------------------------------------------------------------
__global__ __launch_bounds__(256) void att_fused(
    const float* __restrict__ qkv, ushort_t* __restrict__ attout) {
  __shared__ float k_s[128][68];
  __shared__ float v_s[128][68];
  __shared__ float s_s[128][129];
  __shared__ float pm[2][128];
  __shared__ float ps[2][128];
  const int bh = blockIdx.x, b = bh >> 2, h = bh & 3;
  const int t = threadIdx.x;
  const float* base = qkv + (size_t)b * 128 * 768 + h * 64;
  for (int e = t; e < 128 * 64; e += 256) {
    const int n = e >> 6, d = e & 63;
    k_s[n][d] = base[(size_t)n * 768 + 256 + d];
    v_s[n][d] = base[(size_t)n * 768 + 512 + d];
  }
  const int row = t & 127, kh = t >> 7;
  fx4 qr[16];
  const fx4* qrow = (const fx4*)(base + (size_t)row * 768);
  #pragma unroll
  for (int c = 0; c < 16; ++c) qr[c] = qrow[c];
  __syncthreads();
  float m = -1e30f;
  for (int j = 0; j < 64; ++j) {
    const int jj = kh * 64 + j;
    const fx4* kr = (const fx4*)&k_s[jj][0];
    float s0 = 0.f, s1 = 0.f, s2 = 0.f, s3 = 0.f;
    #pragma unroll
    for (int c = 0; c < 16; c += 4) {
      fx4 k0 = kr[c], k1 = kr[c + 1], k2 = kr[c + 2], k3 = kr[c + 3];
      s0 += qr[c][0]*k0[0] + qr[c][1]*k0[1] + qr[c][2]*k0[2] + qr[c][3]*k0[3];
      s1 += qr[c+1][0]*k1[0] + qr[c+1][1]*k1[1] + qr[c+1][2]*k1[2] + qr[c+1][3]*k1[3];
      s2 += qr[c+2][0]*k2[0] + qr[c+2][1]*k2[1] + qr[c+2][2]*k2[2] + qr[c+2][3]*k2[3];
      s3 += qr[c+3][0]*k3[0] + qr[c+3][1]*k3[1] + qr[c+3][2]*k3[2] + qr[c+3][3]*k3[3];
    }
    const float s = (s0 + s1 + s2 + s3) * 0.125f;
    s_s[row][jj] = s;
    m = fmaxf(m, s);
  }
  pm[kh][row] = m;
  __syncthreads();
  const float m2 = fmaxf(pm[0][row], pm[1][row]);
  float sum = 0.f;
  for (int j = 0; j < 64; ++j) {
    const int jj = kh * 64 + j;
    const float e = __expf(s_s[row][jj] - m2);
    s_s[row][jj] = e;
    sum += e;
  }
  ps[kh][row] = sum;
  __syncthreads();
  const int row2 = t >> 1, dh = (t & 1) * 32;
  const float inv = 1.f / (ps[0][row2] + ps[1][row2]);
  fx4 acc4[8] = {};
  for (int k = 0; k < 128; ++k) {
    const float e = s_s[row2][k];
    const fx4* vr = (const fx4*)&v_s[k][dh];
    #pragma unroll
    for (int c = 0; c < 8; ++c) acc4[c] += e * vr[c];
  }
  ushort_t* orow = attout + (size_t)(b * 128 + row2) * 256 + h * 64 + dh;
  #pragma unroll
  for (int c = 0; c < 8; ++c) {
    const fx4 v = acc4[c] * inv;
    s16x4 w;
    #pragma unroll
    for (int j = 0; j < 4; ++j) w[j] = f2bf(v[j]);
    *(s16x4*)(orow + c * 4) = w;
  }
}

// ---------------------------------------------------------------------------
__global__ __launch_bounds__(256) void pool_kernel(
    const float* __restrict__ y2, float* __restrict__ pooled4) {
  const int bq = blockIdx.x;
  const int b = bq >> 2, q = bq & 3, h = threadIdx.x;
  const float* pb = y2 + ((size_t)b * 128 + q * 32) * 256 + h;
  float s = 0.f;
  for (int n = 0; n < 32; ++n) s += pb[(size_t)n * 256];
  pooled4[(size_t)bq * 256 + h] = s;
}

__global__ __launch_bounds__(256) void head_kernel(
    const float* __restrict__ pooled4, const float* __restrict__ W3,
    const float* __restrict__ b3, const float* __restrict__ W4,
    const float* __restrict__ b4, float* __restrict__ out) {
  __shared__ float sp[256];
  __shared__ float t1[256];
  __shared__ float logits[16];
  const int b = blockIdx.x, h = threadIdx.x;
  sp[h] = pooled4[(size_t)(b * 4 + 0) * 256 + h] +
          pooled4[(size_t)(b * 4 + 1) * 256 + h] +
          pooled4[(size_t)(b * 4 + 2) * 256 + h] +
          pooled4[(size_t)(b * 4 + 3) * 256 + h];
  __syncthreads();
  float a = b3[h];
  for (int k = 0; k < 256; ++k) a += sp[k] * W3[k * 256 + h];
  t1[h] = fmaxf(a, 0.f);
  __syncthreads();
  if (h < 16) {
    float o = b4[h];
    for (int j = 0; j < 256; ++j) o += t1[j] * W4[j * 16 + h];
    logits[h] = o;
  }
  __syncthreads();
  if (h < 16) {
    float mm = -1e30f;
    #pragma unroll
    for (int c = 0; c < 16; ++c) mm = fmaxf(mm, logits[c]);
    float se = 0.f;
    #pragma unroll
    for (int c = 0; c < 16; ++c) se += __expf(logits[c] - mm);
    out[b * 16 + h] = logits[h] - mm - logf(se);
  }
}

// ---------------------------------------------------------------------------
extern "C" void kernel_launch(void* const* d_in, const int* in_sizes, int n_in,
                              void* d_out, int out_size, void* d_ws, size_t ws_size,
                              hipStream_t stream) {
  const float* x_in  = (const float*)d_in[0];
  const float* adj   = (const float*)d_in[1];
  const float* W1    = (const float*)d_in[4];
  const float* b1    = (const float*)d_in[5];
  const float* in_w  = (const float*)d_in[6];
  const float* in_b  = (const float*)d_in[7];
  const float* out_w = (const float*)d_in[8];
  const float* out_b = (const float*)d_in[9];
  const float* ln1_s = (const float*)d_in[10];
  const float* ln1_b = (const float*)d_in[11];
  const float* ff1_w = (const float*)d_in[12];
  const float* ff1_b = (const float*)d_in[13];
  const float* ff2_w = (const float*)d_in[14];
  const float* ff2_b = (const float*)d_in[15];
  const float* ln2_s = (const float*)d_in[16];
  const float* ln2_b = (const float*)d_in[17];
  const float* W3    = (const float*)d_in[18];
  const float* b3    = (const float*)d_in[19];
  const float* W4    = (const float*)d_in[20];
  const float* b4    = (const float*)d_in[21];
  char* ws = (char*)d_ws;
  const size_t MB = 1ull << 20;
  ushort_t* xT      = (ushort_t*)(ws);                 // 4 MB
  ushort_t* W1t     = (ushort_t*)(ws + 4 * MB);
  ushort_t* in_wT   = (ushort_t*)(ws + 4 * MB + 131072);
  ushort_t* out_wT  = (ushort_t*)(ws + 4 * MB + 524288);
  ushort_t* ff1t    = (ushort_t*)(ws + 4 * MB + 655360);
  ushort_t* ff2t    = (ushort_t*)(ws + 4 * MB + 917504);
  float*    p       = (float*)(ws + 8 * MB);           // 8 MB
  ushort_t* p_bf    = (ushort_t*)(ws + 16 * MB);       // 4 MB
  float*    qkvb    = (float*)(ws + 20 * MB);          // 24 MB
  ushort_t* attout  = (ushort_t*)(ws + 44 * MB);       // 4 MB
  float*    y       = (float*)(ws + 48 * MB);          // 8 MB
  ushort_t* y_bf    = (ushort_t*)(ws + 56 * MB);       // 4 MB
  ushort_t* f1_bf   = (ushort_t*)(ws + 60 * MB);       // 8 MB
  float*    y2      = (float*)(ws + 68 * MB);          // 8 MB
  float*    pooled4 = (float*)(ws + 76 * MB);          // 256 KB
  float*    part    = (float*)(ws + 77 * MB);          // 32 MB
  float*    outp    = (float*)d_out;
  (void)in_sizes; (void)n_in; (void)out_size; (void)ws_size;

  prep_kernel<<<2304, 256, 0, stream>>>(W1, in_w, out_w, ff1_w, ff2_w,
                                        W1t, in_wT, out_wT, ff1t, ff2t);
  // fc1: xT = (x_in@W1+b1)^T bf16
  mgemm<true, false, false, false, false, true, false>
      <<<dim3(1, 256), 256, 0, stream>>>(
      x_in, W1t, b1, nullptr, nullptr, nullptr, nullptr, xT, 8192, 256, 256);
  // p = relu(adj @ x)
  adjmm_kernel<<<dim3(4, 128), 256, 0, stream>>>(adj, xT, part);
  relu_reduce4<<<2048, 256, 0, stream>>>(part, p, p_bf);
  // qkv (fp32 out for attention)
  mgemm<false, false, false, true, false, false, false>
      <<<dim3(3, 256), 256, 0, stream>>>(
      p_bf, in_wT, in_b, nullptr, nullptr, nullptr, qkvb, nullptr, 8192, 768, 256);
  // attention (fused)
  att_fused<<<256, 256, 0, stream>>>(qkvb, attout);
  // out projection + residual(p) + LN1 -> y (fp32) + y_bf (bf16)
  mgemm<false, false, true, true, true, false, true>
      <<<dim3(1, 256), 256, 0, stream>>>(
      attout, out_wT, out_b, p, ln1_s, ln1_b, y, y_bf, 8192, 256, 256);
  // ff1 (relu, bf16 out)
  mgemm<false, true, false, false, true, false, false>
      <<<dim3(2, 256), 256, 0, stream>>>(
      y_bf, ff1t, ff1_b, nullptr, nullptr, nullptr, nullptr, f1_bf,
      8192, 512, 256);
  // ff2 + residual(y) + LN2 -> y2
  mgemm<false, false, true, true, false, false, true>
      <<<dim3(1, 256), 256, 0, stream>>>(
      f1_bf, ff2t, ff2_b, y, ln2_s, ln2_b, y2, nullptr, 8192, 256, 512);
  // pooling + classifier head
  pool_kernel<<<256, 256, 0, stream>>>(y2, pooled4);
  head_kernel<<<64, 256, 0, stream>>>(pooled4, W3, b3, W4, b4, outp);
}